// Round 3
// baseline (374.946 us; speedup 1.0000x reference)
//
#include <hip/hip_runtime.h>
#include <hip/hip_bf16.h>
#include <cstddef>

#define NN 2000
#define CC 4
#define LL1 5000
#define LL2 1248   /* (5000-11)/4+1 */
#define LL3 207    /* (1248-11)/6+1 */
#define FSTR 208   /* feat row stride (207 + 1 zero pad) */
#define HH 512
#define EE 64000

// ---------------- device-global scratch ----------------
__device__ float g_feat[NN * FSTR];
__device__ float g_aggf[NN * FSTR];
__device__ float g_z[NN * HH];
__device__ float g_xl[NN * HH];
__device__ float g_obuf[NN * HH];
__device__ float g_dinv[NN];
__device__ float g_colsum[HH];
__device__ float g_colsq[HH];
__device__ int   g_cnt[NN];     // zeroed by bn_apply of PREVIOUS replay (init: static 0)
__device__ int   g_cursor[NN];  // ditto
__device__ int   g_off[NN];
__device__ int   g_bucket[EE];

// ---------------- per-node conv chain -------------------------------------
// LDS cut 40.4KB -> ~25.3KB (6 blocks/CU, 24 waves): full sy[4][1248] replaced
// by per-chunk syc[4][312] + 6-pos double-buffered carry head; stage3 (conv3)
// fused per chunk into the same phase as next chunk's stage1 (disjoint LDS).
// Also folds: colsum/colsq zeroing (blocks 0-1) and edge_count (blocks 0-249).
#define MCH 1256
__global__ __launch_bounds__(256) void conv_chain(
    const float* __restrict__ x, const int* __restrict__ ei, const int E,
    const float* __restrict__ w1, const float* __restrict__ b1,
    const float* __restrict__ w2, const float* __restrict__ b2,
    const float* __restrict__ w3, const float* __restrict__ b3)
{
    __shared__ __align__(16) float sm[4 * MCH];      // 20096 B
    __shared__ __align__(16) float syc[4 * 312];     //  4992 B
    __shared__ float hb[2][4][6];                    //   192 B

    const int tid = threadIdx.x;
    const int node = blockIdx.x;

    // colsum/colsq must be zero before gemm_gate accumulates (this kernel runs first)
    if (node < 2) {
        int i = node * 256 + tid;
        g_colsum[i] = 0.f; g_colsq[i] = 0.f;
    }
    // folded edge_count: independent of conv work; g_cnt was zeroed last replay
    if (node < 250) {
        for (int e = node * 256 + tid; e < E; e += 250 * 256)
            atomicAdd(&g_cnt[ei[E + e]], 1);
    }

    const float* xb = x + (size_t)node * (CC * LL1);

    float w1r[64], b1r[16];
#pragma unroll
    for (int i = 0; i < 64; ++i) w1r[i] = w1[i];
#pragma unroll
    for (int i = 0; i < 16; ++i) b1r[i] = b1[i];

    float4 xA[2][4], xB[2][4];

    auto issueL = [&](int cc, float4 (&dst)[2][4]) {
#pragma unroll
        for (int it = 0; it < 2; ++it) {
            const int g4 = tid + it * 256;
            if (g4 < 314) {
                const int l = 1248 * cc + 4 * g4;
#pragma unroll
                for (int ch = 0; ch < 4; ++ch)
                    dst[it][ch] = *(const float4*)(xb + ch * LL1 + l);
            }
        }
    };

    auto stage1 = [&](float4 (&src)[2][4]) {
#pragma unroll
        for (int it = 0; it < 2; ++it) {
            const int g4 = tid + it * 256;
            if (g4 < 314) {
                float xs[4][4];
#pragma unroll
                for (int ch = 0; ch < 4; ++ch)
                    *(float4*)xs[ch] = src[it][ch];
#pragma unroll
                for (int g = 0; g < 4; ++g) {
                    float mv[4];
#pragma unroll
                    for (int li = 0; li < 4; ++li) {
                        float best = -1e30f;
#pragma unroll
                        for (int j = 0; j < 4; ++j) {
                            int o = g * 4 + j;
                            float v = b1r[o] + w1r[o*4+0]*xs[0][li] + w1r[o*4+1]*xs[1][li]
                                             + w1r[o*4+2]*xs[2][li] + w1r[o*4+3]*xs[3][li];
                            best = fmaxf(best, v);
                        }
                        mv[li] = fmaxf(best, 0.f);
                    }
                    *(float4*)&sm[g * MCH + 4 * g4] = make_float4(mv[0], mv[1], mv[2], mv[3]);
                }
            }
        }
    };

    auto stage2 = [&](int cc) {
        (void)cc;
#pragma unroll 1
        for (int pair = 0; pair < 2; ++pair) {
            const float* wp = w2 + 88 * pair;
            float wo[88];
#pragma unroll
            for (int i = 0; i < 88; ++i) wo[i] = wp[i];
            const float bo0 = b2[2 * pair], bo1 = b2[2 * pair + 1];
            for (int T = tid; T < 312; T += 256) {
                float a0 = bo0, a1 = bo1;
#pragma unroll
                for (int i = 0; i < 4; ++i) {
                    const float* mp = sm + i * MCH + 4 * T;
                    float4 u0 = *(const float4*)mp;
                    float4 u1 = *(const float4*)(mp + 4);
                    float4 u2 = *(const float4*)(mp + 8);
                    float v[12] = {u0.x, u0.y, u0.z, u0.w,
                                   u1.x, u1.y, u1.z, u1.w,
                                   u2.x, u2.y, u2.z, u2.w};
#pragma unroll
                    for (int k = 0; k < 11; ++k) {
                        a0 += wo[i * 11 + k] * v[k];
                        a1 += wo[44 + i * 11 + k] * v[k];
                    }
                }
                syc[(2 * pair) * 312 + T]     = fmaxf(a0, 0.f);
                syc[(2 * pair + 1) * 312 + T] = fmaxf(a1, 0.f);
            }
        }
    };

    // stage3 for chunk cc: outputs t in [tlo, thi]; first output of chunks>=1
    // taps the 6 carried positions in hb[cc&1].
    auto stage3 = [&](int cc) {
        const int cnt = cc ? 52 : 51;
        if (tid < cnt) {
            const int t = cc ? (52 * cc - 1 + tid) : tid;
            const int T0 = 312 * cc;
            float acc = b3[0];
#pragma unroll
            for (int i = 0; i < 4; ++i)
#pragma unroll
                for (int k = 0; k < 11; ++k) {
                    const int q = 6 * t + k - T0;
                    const float v = (q < 0) ? hb[cc & 1][i][q + 6] : syc[i * 312 + q];
                    acc += w3[i * 11 + k] * v;
                }
            g_feat[(size_t)node * FSTR + t] = fmaxf(acc, 0.f);
        }
    };

    // copy last 6 positions of chunk (cc-1)'s syc into head buffer for chunk cc
    auto copyhead = [&](int cc) {
        const int th = tid - 52;
        if (th >= 0 && th < 24) {
            const int ch = th / 6, j = th - 6 * ch;
            hb[cc & 1][ch][j] = syc[ch * 312 + 306 + j];
        }
    };

    issueL(0, xA);
    issueL(1, xB);
    stage1(xA);                                   // sm chunk0
    __syncthreads();
    issueL(2, xA);
    stage2(0);                                    // syc chunk0
    __syncthreads();
    stage1(xB); stage3(0); copyhead(1);           // sm chunk1 | conv3 chunk0
    __syncthreads();
    issueL(3, xB);
    stage2(1);
    __syncthreads();
    stage1(xA); stage3(1); copyhead(2);
    __syncthreads();
    stage2(2);
    __syncthreads();
    stage1(xB); stage3(2); copyhead(3);
    __syncthreads();
    stage2(3);
    __syncthreads();
    stage3(3);
    if (tid == 52) g_feat[(size_t)node * FSTR + 207] = 0.f;   // pad column
}

// ---------------- scan + dinv (1 block, shuffle scan, 1 barrier) ----------------
__global__ __launch_bounds__(256) void scan_dinv() {
    const int tid = threadIdx.x;
    const int base = tid * 8;
    int c[8];
#pragma unroll
    for (int k = 0; k < 8; ++k) c[k] = (base + k < NN) ? g_cnt[base + k] : 0;
    int pre[8]; int s = 0;
#pragma unroll
    for (int k = 0; k < 8; ++k) { pre[k] = s; s += c[k]; }
    const int lane = tid & 63;
    int ws = s;
#pragma unroll
    for (int d = 1; d < 64; d <<= 1) {
        int t = __shfl_up(ws, d, 64);
        if (lane >= d) ws += t;
    }
    __shared__ int wsum[4];
    const int wid = tid >> 6;
    if (lane == 63) wsum[wid] = ws;
    __syncthreads();
    int woff = 0;
#pragma unroll
    for (int w = 0; w < 4; ++w) if (w < wid) woff += wsum[w];
    const int toff = woff + ws - s;
#pragma unroll
    for (int k = 0; k < 8; ++k) {
        const int i = base + k;
        if (i < NN) {
            g_off[i] = toff + pre[k];
            g_dinv[i] = rsqrtf(1.0f + (float)c[k]);
        }
    }
}

__global__ void bucket_fill(const int* __restrict__ ei, int E) {
    int e = blockIdx.x * 256 + threadIdx.x;
    if (e < E) {
        int d = ei[E + e];
        int p = atomicAdd(&g_cursor[d], 1);
        g_bucket[g_off[d] + p] = ei[e];
    }
}

// ---------------- aggregate feat over graph (float4 gathers, 4 nodes/block) -------
__global__ __launch_bounds__(256) void agg_feat() {
    const int sub = threadIdx.x >> 6;
    const int lane = threadIdx.x & 63;
    const int d = blockIdx.x * 4 + sub;          // grid 500 -> d < 2000
    if (lane >= 52) return;
    const float di = g_dinv[d];
    const int nb = g_cnt[d];
    const int base = g_off[d];
    const size_t co = (size_t)lane * 4;
    float4 a = *(const float4*)(g_feat + (size_t)d * FSTR + co);
    float ax = a.x * di, ay = a.y * di, az = a.z * di, aw = a.w * di;
    int j = 0;
    for (; j + 1 < nb; j += 2) {
        int s0 = g_bucket[base + j];
        int s1 = g_bucket[base + j + 1];
        float w0 = g_dinv[s0], w1 = g_dinv[s1];
        float4 f0 = *(const float4*)(g_feat + (size_t)s0 * FSTR + co);
        float4 f1 = *(const float4*)(g_feat + (size_t)s1 * FSTR + co);
        ax += f0.x * w0 + f1.x * w1;
        ay += f0.y * w0 + f1.y * w1;
        az += f0.z * w0 + f1.z * w1;
        aw += f0.w * w0 + f1.w * w1;
    }
    if (j < nb) {
        int s = g_bucket[base + j];
        float w = g_dinv[s];
        float4 f = *(const float4*)(g_feat + (size_t)s * FSTR + co);
        ax += f.x * w; ay += f.y * w; az += f.z * w; aw += f.w * w;
    }
    *(float4*)(g_aggf + (size_t)d * FSTR + co) = make_float4(ax * di, ay * di, az * di, aw * di);
}

// ---------------- GEMM 64x64 tile, 256 thr, 4x4 micro-tile, dbuf ----------------
__global__ __launch_bounds__(256) void gemm_zxl(
    const float* __restrict__ gcn_w, const float* __restrict__ gcn_b,
    const float* __restrict__ lin_w, const float* __restrict__ lin_b)
{
    __shared__ __align__(16) float As[2][16][68];
    __shared__ __align__(16) float Bs[2][16][68];
    const int tid = threadIdx.x;
    const int which = blockIdx.z;
    const float* __restrict__ A = which ? g_feat : g_aggf;
    const float* __restrict__ B = which ? lin_w : gcn_w;
    const float* __restrict__ bias = which ? lin_b : gcn_b;
    float* __restrict__ C = which ? g_xl : g_z;
    const int N0 = blockIdx.x * 64, M0 = blockIdx.y * 64;
    const int ar = tid >> 2, ak = (tid & 3) * 4;   // A loader
    const int bk = tid >> 4, bn = (tid & 15) * 4;  // B loader
    const int ty = tid >> 4, tx = tid & 15;        // compute 4x4
    const int rowA = M0 + ar;

    float acc[16];
#pragma unroll
    for (int i = 0; i < 16; ++i) acc[i] = 0.f;
    const float4 z4 = make_float4(0.f, 0.f, 0.f, 0.f);
    float4 rA, rB;

    rA = (rowA < NN) ? *(const float4*)(A + (size_t)rowA * FSTR + ak) : z4;
    rB = (bk < LL3) ? *(const float4*)(B + (size_t)bk * HH + N0 + bn) : z4;
    As[0][ak+0][ar] = rA.x; As[0][ak+1][ar] = rA.y;
    As[0][ak+2][ar] = rA.z; As[0][ak+3][ar] = rA.w;
    *(float4*)&Bs[0][bk][bn] = rB;
    __syncthreads();

#pragma unroll 1
    for (int kt = 0; kt < 13; ++kt) {              // 13*16 = 208 = FSTR (pad col = 0)
        const int cur = kt & 1;
        if (kt + 1 < 13) {
            const int k0 = (kt + 1) * 16;
            rA = (rowA < NN) ? *(const float4*)(A + (size_t)rowA * FSTR + k0 + ak) : z4;
            const int kb = k0 + bk;
            rB = (kb < LL3) ? *(const float4*)(B + (size_t)kb * HH + N0 + bn) : z4;
        }
#pragma unroll
        for (int k = 0; k < 16; ++k) {
            const float4 a4 = *(const float4*)&As[cur][k][ty * 4];
            const float4 b4 = *(const float4*)&Bs[cur][k][tx * 4];
            const float av[4] = {a4.x, a4.y, a4.z, a4.w};
            const float bv[4] = {b4.x, b4.y, b4.z, b4.w};
#pragma unroll
            for (int i = 0; i < 4; ++i)
#pragma unroll
                for (int j = 0; j < 4; ++j)
                    acc[i * 4 + j] += av[i] * bv[j];
        }
        if (kt + 1 < 13) {
            const int nxt = cur ^ 1;
            As[nxt][ak+0][ar] = rA.x; As[nxt][ak+1][ar] = rA.y;
            As[nxt][ak+2][ar] = rA.z; As[nxt][ak+3][ar] = rA.w;
            *(float4*)&Bs[nxt][bk][bn] = rB;
        }
        __syncthreads();
    }

    const int c0 = N0 + tx * 4;
    const float4 bb = *(const float4*)(bias + c0);
#pragma unroll
    for (int i = 0; i < 4; ++i) {
        const int r = M0 + ty * 4 + i;
        if (r < NN) {
            float4 v = make_float4(acc[i*4+0] + bb.x, acc[i*4+1] + bb.y,
                                   acc[i*4+2] + bb.z, acc[i*4+3] + bb.w);
            if (which == 0) { v.x = tanhf(v.x); v.y = tanhf(v.y); v.z = tanhf(v.z); v.w = tanhf(v.w); }
            *(float4*)(C + (size_t)r * HH + c0) = v;
        }
    }
}

// gate GEMM: gpre = z @ gate_w + gate_b, fused sigmoid-gate/residual/relu/colsums
__global__ __launch_bounds__(256) void gemm_gate(
    const float* __restrict__ gate_w, const float* __restrict__ gate_b)
{
    __shared__ __align__(16) float As[2][16][68];
    __shared__ __align__(16) float Bs[2][16][68];
    __shared__ float rs[64], rq[64];
    const int tid = threadIdx.x;
    const float* __restrict__ A = g_z;
    const int N0 = blockIdx.x * 64, M0 = blockIdx.y * 64;
    const int ar = tid >> 2, ak = (tid & 3) * 4;
    const int bk = tid >> 4, bn = (tid & 15) * 4;
    const int ty = tid >> 4, tx = tid & 15;
    const int rowA = M0 + ar;

    float acc[16];
#pragma unroll
    for (int i = 0; i < 16; ++i) acc[i] = 0.f;
    const float4 z4 = make_float4(0.f, 0.f, 0.f, 0.f);
    float4 rA, rB;

    rA = (rowA < NN) ? *(const float4*)(A + (size_t)rowA * HH + ak) : z4;
    rB = *(const float4*)(gate_w + (size_t)bk * HH + N0 + bn);
    As[0][ak+0][ar] = rA.x; As[0][ak+1][ar] = rA.y;
    As[0][ak+2][ar] = rA.z; As[0][ak+3][ar] = rA.w;
    *(float4*)&Bs[0][bk][bn] = rB;
    __syncthreads();

#pragma unroll 1
    for (int kt = 0; kt < 32; ++kt) {              // 32*16 = 512 = HH
        const int cur = kt & 1;
        if (kt + 1 < 32) {
            const int k0 = (kt + 1) * 16;
            rA = (rowA < NN) ? *(const float4*)(A + (size_t)rowA * HH + k0 + ak) : z4;
            rB = *(const float4*)(gate_w + (size_t)(k0 + bk) * HH + N0 + bn);
        }
#pragma unroll
        for (int k = 0; k < 16; ++k) {
            const float4 a4 = *(const float4*)&As[cur][k][ty * 4];
            const float4 b4 = *(const float4*)&Bs[cur][k][tx * 4];
            const float av[4] = {a4.x, a4.y, a4.z, a4.w};
            const float bv[4] = {b4.x, b4.y, b4.z, b4.w};
#pragma unroll
            for (int i = 0; i < 4; ++i)
#pragma unroll
                for (int j = 0; j < 4; ++j)
                    acc[i * 4 + j] += av[i] * bv[j];
        }
        if (kt + 1 < 32) {
            const int nxt = cur ^ 1;
            As[nxt][ak+0][ar] = rA.x; As[nxt][ak+1][ar] = rA.y;
            As[nxt][ak+2][ar] = rA.z; As[nxt][ak+3][ar] = rA.w;
            *(float4*)&Bs[nxt][bk][bn] = rB;
        }
        __syncthreads();
    }

    const int c0 = N0 + tx * 4;
    const float4 bb = *(const float4*)(gate_b + c0);
    float cs[4] = {0.f, 0.f, 0.f, 0.f}, cq[4] = {0.f, 0.f, 0.f, 0.f};
#pragma unroll
    for (int i = 0; i < 4; ++i) {
        const int r = M0 + ty * 4 + i;
        if (r < NN) {
            const float4 xv = *(const float4*)(g_xl + (size_t)r * HH + c0);
            const float4 zv = *(const float4*)(g_z + (size_t)r * HH + c0);
            const float pre[4] = {acc[i*4+0] + bb.x, acc[i*4+1] + bb.y,
                                  acc[i*4+2] + bb.z, acc[i*4+3] + bb.w};
            const float xa[4] = {xv.x, xv.y, xv.z, xv.w};
            const float za[4] = {zv.x, zv.y, zv.z, zv.w};
            float va[4];
#pragma unroll
            for (int j = 0; j < 4; ++j) {
                float g = 1.f / (1.f + __expf(-pre[j]));
                float v = fmaxf((1.f - g) * xa[j] + g * za[j], 0.f);
                va[j] = v; cs[j] += v; cq[j] += v * v;
            }
            *(float4*)(g_obuf + (size_t)r * HH + c0) = make_float4(va[0], va[1], va[2], va[3]);
        }
    }
    if (tid < 64) { rs[tid] = 0.f; rq[tid] = 0.f; }
    __syncthreads();
#pragma unroll
    for (int j = 0; j < 4; ++j) {
        atomicAdd(&rs[tx * 4 + j], cs[j]);
        atomicAdd(&rq[tx * 4 + j], cq[j]);
    }
    __syncthreads();
    if (tid < 64) {
        atomicAdd(&g_colsum[N0 + tid], rs[tid]);
        atomicAdd(&g_colsq[N0 + tid], rq[tid]);
    }
}

// ---------------- BN apply with inline stats; re-zeroes cnt/cursor for next replay ----
__global__ __launch_bounds__(256) void bn_apply(const float* __restrict__ gamma,
                                                const float* __restrict__ beta,
                                                float* __restrict__ out) {
    if (blockIdx.x < 8) {
        int i = blockIdx.x * 256 + threadIdx.x;
        if (i < NN) { g_cnt[i] = 0; g_cursor[i] = 0; }  // consumed last by agg_feat; safe here
    }
    int i = blockIdx.x * 256 + threadIdx.x;  // exactly NN*HH
    int c = i & (HH - 1);
    float mean = g_colsum[c] * (1.f / (float)NN);
    float var = g_colsq[c] * (1.f / (float)NN) - mean * mean;
    float s = rsqrtf(var + 1e-5f) * gamma[c];
    out[i] = g_obuf[i] * s + (beta[c] - mean * s);
}

// ---------------- launch ----------------
extern "C" void kernel_launch(void* const* d_in, const int* in_sizes, int n_in,
                              void* d_out, int out_size, void* d_ws, size_t ws_size,
                              hipStream_t stream) {
    (void)d_ws; (void)ws_size; (void)n_in; (void)out_size;
    const float* x      = (const float*)d_in[0];
    const int*   ei     = (const int*)d_in[1];
    const float* w1     = (const float*)d_in[2];
    const float* b1     = (const float*)d_in[3];
    const float* w2     = (const float*)d_in[4];
    const float* b2     = (const float*)d_in[5];
    const float* w3     = (const float*)d_in[6];
    const float* b3     = (const float*)d_in[7];
    const float* gcn_w  = (const float*)d_in[8];
    const float* gcn_b  = (const float*)d_in[9];
    const float* lin_w  = (const float*)d_in[10];
    const float* lin_b  = (const float*)d_in[11];
    const float* gate_w = (const float*)d_in[12];
    const float* gate_b = (const float*)d_in[13];
    const float* bn_g   = (const float*)d_in[14];
    const float* bn_b   = (const float*)d_in[15];
    float* out = (float*)d_out;
    const int E = in_sizes[1] / 2;

    conv_chain<<<NN, 256, 0, stream>>>(x, ei, E, w1, b1, w2, b2, w3, b3);
    scan_dinv<<<1, 256, 0, stream>>>();
    bucket_fill<<<(E + 255) / 256, 256, 0, stream>>>(ei, E);
    agg_feat<<<NN / 4, 256, 0, stream>>>();

    gemm_zxl<<<dim3(HH / 64, (NN + 63) / 64, 2), 256, 0, stream>>>(gcn_w, gcn_b, lin_w, lin_b);
    gemm_gate<<<dim3(HH / 64, (NN + 63) / 64), 256, 0, stream>>>(gate_w, gate_b);

    bn_apply<<<(NN * HH) / 256, 256, 0, stream>>>(bn_g, bn_b, out);
}

// Round 4
// 365.699 us; speedup vs baseline: 1.0253x; 1.0253x over previous
//
#include <hip/hip_runtime.h>
#include <hip/hip_bf16.h>
#include <cstddef>

#define NN 2000
#define CC 4
#define LL1 5000
#define LL2 1248   /* (5000-11)/4+1 */
#define LL3 207    /* (1248-11)/6+1 */
#define FSTR 208   /* feat row stride (207 + 1 zero pad) */
#define HH 512
#define EE 64000

// ---------------- device-global scratch ----------------
__device__ float g_feat[NN * FSTR];
__device__ float g_aggf[NN * FSTR];
__device__ float g_z[NN * HH];
__device__ float g_xl[NN * HH];
__device__ float g_obuf[NN * HH];
__device__ float g_dinv[NN];
__device__ float g_colsum[HH];
__device__ float g_colsq[HH];
__device__ int   g_cnt[NN];     // zeroed by bn_apply of PREVIOUS replay (init: static 0)
__device__ int   g_cursor[NN];  // ditto
__device__ int   g_off[NN];
__device__ int   g_bucket[EE];

// ---------------- per-node conv chain: wave-autonomous, 1 barrier/node ----------
// Each wave owns T-blocks of 61 conv2 outputs (21 blocks round-robin over 4 waves).
// Per block: load 256-pos x window (1 float4/lane/ch, prefetched), conv1+maxpool
// into WAVE-PRIVATE LDS strip (no cross-wave hazard -> no barrier), conv2 all 4
// out-ch/thread (weights uniform->SGPR), write sy. Single __syncthreads before conv3.
// R3 lesson: occupancy/LDS size irrelevant; barrier-imbalance (VALUBusy 44%) is the target.
__global__ __launch_bounds__(256) void conv_chain(
    const float* __restrict__ x, const int* __restrict__ ei, const int E,
    const float* __restrict__ w1, const float* __restrict__ b1,
    const float* __restrict__ w2, const float* __restrict__ b2,
    const float* __restrict__ w3, const float* __restrict__ b3)
{
    __shared__ __align__(16) float sy[4][LL2];        // 19968 B  (shared: conv3 crosses waves)
    __shared__ __align__(16) float smw[4][4][256];    // 16384 B  [wave][ch][local pos] private

    const int tid  = threadIdx.x;
    const int node = blockIdx.x;
    const int wid  = tid >> 6;
    const int lane = tid & 63;

    // colsum/colsq must be zero before gemm_gate accumulates (this kernel runs first)
    if (node < 2) {
        int i = node * 256 + tid;
        g_colsum[i] = 0.f; g_colsq[i] = 0.f;
    }
    // folded edge_count: independent of conv work; g_cnt was zeroed last replay
    if (node < 250) {
        for (int e = node * 256 + tid; e < E; e += 250 * 256)
            atomicAdd(&g_cnt[ei[E + e]], 1);
    }

    const float* xb = x + (size_t)node * (CC * LL1);

    // uniform weights -> compiler promotes to SGPR (verified: VGPR=64 in prior build)
    float w1r[64], b1r[16];
#pragma unroll
    for (int i = 0; i < 64; ++i) w1r[i] = w1[i];
#pragma unroll
    for (int i = 0; i < 16; ++i) b1r[i] = b1[i];

    auto loadx = [&](int bb, float4 (&dst)[4]) {
        const int p = 244 * bb + 4 * lane;
        const bool ok = (p + 3) < LL1;
#pragma unroll
        for (int ch = 0; ch < 4; ++ch)
            dst[ch] = ok ? *(const float4*)(xb + ch * LL1 + p)
                         : make_float4(0.f, 0.f, 0.f, 0.f);
    };

    float4 xc[4], xn[4];
    int b = wid;
    if (b < 21) loadx(b, xc);

    while (b < 21) {
        const int bn = b + 4;
        if (bn < 21) loadx(bn, xn);          // prefetch next block (hidden under compute)

        // ---- stage1: conv1 (k=1) + channel-group maxpool + relu, 4 positions/lane ----
        {
            float xs[4][4];
#pragma unroll
            for (int ch = 0; ch < 4; ++ch)
                *(float4*)xs[ch] = xc[ch];
#pragma unroll
            for (int g = 0; g < 4; ++g) {
                float mv[4];
#pragma unroll
                for (int li = 0; li < 4; ++li) {
                    float best = -1e30f;
#pragma unroll
                    for (int j = 0; j < 4; ++j) {
                        const int o = g * 4 + j;
                        float v = b1r[o] + w1r[o*4+0]*xs[0][li] + w1r[o*4+1]*xs[1][li]
                                         + w1r[o*4+2]*xs[2][li] + w1r[o*4+3]*xs[3][li];
                        best = fmaxf(best, v);
                    }
                    mv[li] = fmaxf(best, 0.f);
                }
                *(float4*)&smw[wid][g][4 * lane] = make_float4(mv[0], mv[1], mv[2], mv[3]);
            }
        }
        // same-wave LDS write->read: in-order LDS pipe + compiler lgkmcnt; no barrier

        // ---- stage2: conv2 stride 4, all 4 out-channels, T = 61*b + lane ----
        {
            const int Tg = 61 * b + lane;
            if (lane < 61 && Tg < LL2) {
                float a0 = b2[0], a1 = b2[1], a2 = b2[2], a3 = b2[3];
#pragma unroll
                for (int i = 0; i < 4; ++i) {
                    const float* mp = &smw[wid][i][4 * lane];   // local pos = 4*lane..+11
                    float4 u0 = *(const float4*)mp;
                    float4 u1 = *(const float4*)(mp + 4);
                    float4 u2 = *(const float4*)(mp + 8);
                    float v[12] = {u0.x, u0.y, u0.z, u0.w,
                                   u1.x, u1.y, u1.z, u1.w,
                                   u2.x, u2.y, u2.z, u2.w};
#pragma unroll
                    for (int k = 0; k < 11; ++k) {
                        a0 += w2[  0 + i * 11 + k] * v[k];
                        a1 += w2[ 44 + i * 11 + k] * v[k];
                        a2 += w2[ 88 + i * 11 + k] * v[k];
                        a3 += w2[132 + i * 11 + k] * v[k];
                    }
                }
                sy[0][Tg] = fmaxf(a0, 0.f);
                sy[1][Tg] = fmaxf(a1, 0.f);
                sy[2][Tg] = fmaxf(a2, 0.f);
                sy[3][Tg] = fmaxf(a3, 0.f);
            }
        }

#pragma unroll
        for (int ch = 0; ch < 4; ++ch) xc[ch] = xn[ch];
        b = bn;
    }

    __syncthreads();   // the ONE barrier: sy complete

    // ---- stage3: conv3 stride 6, 1 out-channel ----
    if (tid < FSTR) {
        float acc = 0.f;
        if (tid < LL3) {
            acc = b3[0];
#pragma unroll
            for (int i = 0; i < 4; ++i)
#pragma unroll
                for (int k = 0; k < 11; ++k)
                    acc += w3[i * 11 + k] * sy[i][6 * tid + k];
            acc = fmaxf(acc, 0.f);
        }
        g_feat[(size_t)node * FSTR + tid] = acc;
    }
}

// ---------------- scan + dinv (1 block, shuffle scan, 1 barrier) ----------------
__global__ __launch_bounds__(256) void scan_dinv() {
    const int tid = threadIdx.x;
    const int base = tid * 8;
    int c[8];
#pragma unroll
    for (int k = 0; k < 8; ++k) c[k] = (base + k < NN) ? g_cnt[base + k] : 0;
    int pre[8]; int s = 0;
#pragma unroll
    for (int k = 0; k < 8; ++k) { pre[k] = s; s += c[k]; }
    const int lane = tid & 63;
    int ws = s;
#pragma unroll
    for (int d = 1; d < 64; d <<= 1) {
        int t = __shfl_up(ws, d, 64);
        if (lane >= d) ws += t;
    }
    __shared__ int wsum[4];
    const int wid = tid >> 6;
    if (lane == 63) wsum[wid] = ws;
    __syncthreads();
    int woff = 0;
#pragma unroll
    for (int w = 0; w < 4; ++w) if (w < wid) woff += wsum[w];
    const int toff = woff + ws - s;
#pragma unroll
    for (int k = 0; k < 8; ++k) {
        const int i = base + k;
        if (i < NN) {
            g_off[i] = toff + pre[k];
            g_dinv[i] = rsqrtf(1.0f + (float)c[k]);
        }
    }
}

__global__ void bucket_fill(const int* __restrict__ ei, int E) {
    int e = blockIdx.x * 256 + threadIdx.x;
    if (e < E) {
        int d = ei[E + e];
        int p = atomicAdd(&g_cursor[d], 1);
        g_bucket[g_off[d] + p] = ei[e];
    }
}

// ---------------- aggregate feat over graph (float4 gathers, 4 nodes/block) -------
__global__ __launch_bounds__(256) void agg_feat() {
    const int sub = threadIdx.x >> 6;
    const int lane = threadIdx.x & 63;
    const int d = blockIdx.x * 4 + sub;          // grid 500 -> d < 2000
    if (lane >= 52) return;
    const float di = g_dinv[d];
    const int nb = g_cnt[d];
    const int base = g_off[d];
    const size_t co = (size_t)lane * 4;
    float4 a = *(const float4*)(g_feat + (size_t)d * FSTR + co);
    float ax = a.x * di, ay = a.y * di, az = a.z * di, aw = a.w * di;
    int j = 0;
    for (; j + 1 < nb; j += 2) {
        int s0 = g_bucket[base + j];
        int s1 = g_bucket[base + j + 1];
        float w0 = g_dinv[s0], w1 = g_dinv[s1];
        float4 f0 = *(const float4*)(g_feat + (size_t)s0 * FSTR + co);
        float4 f1 = *(const float4*)(g_feat + (size_t)s1 * FSTR + co);
        ax += f0.x * w0 + f1.x * w1;
        ay += f0.y * w0 + f1.y * w1;
        az += f0.z * w0 + f1.z * w1;
        aw += f0.w * w0 + f1.w * w1;
    }
    if (j < nb) {
        int s = g_bucket[base + j];
        float w = g_dinv[s];
        float4 f = *(const float4*)(g_feat + (size_t)s * FSTR + co);
        ax += f.x * w; ay += f.y * w; az += f.z * w; aw += f.w * w;
    }
    *(float4*)(g_aggf + (size_t)d * FSTR + co) = make_float4(ax * di, ay * di, az * di, aw * di);
}

// ---------------- GEMM 64x64 tile, 256 thr, 4x4 micro-tile, dbuf ----------------
__global__ __launch_bounds__(256) void gemm_zxl(
    const float* __restrict__ gcn_w, const float* __restrict__ gcn_b,
    const float* __restrict__ lin_w, const float* __restrict__ lin_b)
{
    __shared__ __align__(16) float As[2][16][68];
    __shared__ __align__(16) float Bs[2][16][68];
    const int tid = threadIdx.x;
    const int which = blockIdx.z;
    const float* __restrict__ A = which ? g_feat : g_aggf;
    const float* __restrict__ B = which ? lin_w : gcn_w;
    const float* __restrict__ bias = which ? lin_b : gcn_b;
    float* __restrict__ C = which ? g_xl : g_z;
    const int N0 = blockIdx.x * 64, M0 = blockIdx.y * 64;
    const int ar = tid >> 2, ak = (tid & 3) * 4;   // A loader
    const int bk = tid >> 4, bn = (tid & 15) * 4;  // B loader
    const int ty = tid >> 4, tx = tid & 15;        // compute 4x4
    const int rowA = M0 + ar;

    float acc[16];
#pragma unroll
    for (int i = 0; i < 16; ++i) acc[i] = 0.f;
    const float4 z4 = make_float4(0.f, 0.f, 0.f, 0.f);
    float4 rA, rB;

    rA = (rowA < NN) ? *(const float4*)(A + (size_t)rowA * FSTR + ak) : z4;
    rB = (bk < LL3) ? *(const float4*)(B + (size_t)bk * HH + N0 + bn) : z4;
    As[0][ak+0][ar] = rA.x; As[0][ak+1][ar] = rA.y;
    As[0][ak+2][ar] = rA.z; As[0][ak+3][ar] = rA.w;
    *(float4*)&Bs[0][bk][bn] = rB;
    __syncthreads();

#pragma unroll 1
    for (int kt = 0; kt < 13; ++kt) {              // 13*16 = 208 = FSTR (pad col = 0)
        const int cur = kt & 1;
        if (kt + 1 < 13) {
            const int k0 = (kt + 1) * 16;
            rA = (rowA < NN) ? *(const float4*)(A + (size_t)rowA * FSTR + k0 + ak) : z4;
            const int kb = k0 + bk;
            rB = (kb < LL3) ? *(const float4*)(B + (size_t)kb * HH + N0 + bn) : z4;
        }
#pragma unroll
        for (int k = 0; k < 16; ++k) {
            const float4 a4 = *(const float4*)&As[cur][k][ty * 4];
            const float4 b4 = *(const float4*)&Bs[cur][k][tx * 4];
            const float av[4] = {a4.x, a4.y, a4.z, a4.w};
            const float bv[4] = {b4.x, b4.y, b4.z, b4.w};
#pragma unroll
            for (int i = 0; i < 4; ++i)
#pragma unroll
                for (int j = 0; j < 4; ++j)
                    acc[i * 4 + j] += av[i] * bv[j];
        }
        if (kt + 1 < 13) {
            const int nxt = cur ^ 1;
            As[nxt][ak+0][ar] = rA.x; As[nxt][ak+1][ar] = rA.y;
            As[nxt][ak+2][ar] = rA.z; As[nxt][ak+3][ar] = rA.w;
            *(float4*)&Bs[nxt][bk][bn] = rB;
        }
        __syncthreads();
    }

    const int c0 = N0 + tx * 4;
    const float4 bb = *(const float4*)(bias + c0);
#pragma unroll
    for (int i = 0; i < 4; ++i) {
        const int r = M0 + ty * 4 + i;
        if (r < NN) {
            float4 v = make_float4(acc[i*4+0] + bb.x, acc[i*4+1] + bb.y,
                                   acc[i*4+2] + bb.z, acc[i*4+3] + bb.w);
            if (which == 0) { v.x = tanhf(v.x); v.y = tanhf(v.y); v.z = tanhf(v.z); v.w = tanhf(v.w); }
            *(float4*)(C + (size_t)r * HH + c0) = v;
        }
    }
}

// gate GEMM: gpre = z @ gate_w + gate_b, fused sigmoid-gate/residual/relu/colsums
__global__ __launch_bounds__(256) void gemm_gate(
    const float* __restrict__ gate_w, const float* __restrict__ gate_b)
{
    __shared__ __align__(16) float As[2][16][68];
    __shared__ __align__(16) float Bs[2][16][68];
    __shared__ float rs[64], rq[64];
    const int tid = threadIdx.x;
    const float* __restrict__ A = g_z;
    const int N0 = blockIdx.x * 64, M0 = blockIdx.y * 64;
    const int ar = tid >> 2, ak = (tid & 3) * 4;
    const int bk = tid >> 4, bn = (tid & 15) * 4;
    const int ty = tid >> 4, tx = tid & 15;
    const int rowA = M0 + ar;

    float acc[16];
#pragma unroll
    for (int i = 0; i < 16; ++i) acc[i] = 0.f;
    const float4 z4 = make_float4(0.f, 0.f, 0.f, 0.f);
    float4 rA, rB;

    rA = (rowA < NN) ? *(const float4*)(A + (size_t)rowA * HH + ak) : z4;
    rB = *(const float4*)(gate_w + (size_t)bk * HH + N0 + bn);
    As[0][ak+0][ar] = rA.x; As[0][ak+1][ar] = rA.y;
    As[0][ak+2][ar] = rA.z; As[0][ak+3][ar] = rA.w;
    *(float4*)&Bs[0][bk][bn] = rB;
    __syncthreads();

#pragma unroll 1
    for (int kt = 0; kt < 32; ++kt) {              // 32*16 = 512 = HH
        const int cur = kt & 1;
        if (kt + 1 < 32) {
            const int k0 = (kt + 1) * 16;
            rA = (rowA < NN) ? *(const float4*)(A + (size_t)rowA * HH + k0 + ak) : z4;
            rB = *(const float4*)(gate_w + (size_t)(k0 + bk) * HH + N0 + bn);
        }
#pragma unroll
        for (int k = 0; k < 16; ++k) {
            const float4 a4 = *(const float4*)&As[cur][k][ty * 4];
            const float4 b4 = *(const float4*)&Bs[cur][k][tx * 4];
            const float av[4] = {a4.x, a4.y, a4.z, a4.w};
            const float bv[4] = {b4.x, b4.y, b4.z, b4.w};
#pragma unroll
            for (int i = 0; i < 4; ++i)
#pragma unroll
                for (int j = 0; j < 4; ++j)
                    acc[i * 4 + j] += av[i] * bv[j];
        }
        if (kt + 1 < 32) {
            const int nxt = cur ^ 1;
            As[nxt][ak+0][ar] = rA.x; As[nxt][ak+1][ar] = rA.y;
            As[nxt][ak+2][ar] = rA.z; As[nxt][ak+3][ar] = rA.w;
            *(float4*)&Bs[nxt][bk][bn] = rB;
        }
        __syncthreads();
    }

    const int c0 = N0 + tx * 4;
    const float4 bb = *(const float4*)(gate_b + c0);
    float cs[4] = {0.f, 0.f, 0.f, 0.f}, cq[4] = {0.f, 0.f, 0.f, 0.f};
#pragma unroll
    for (int i = 0; i < 4; ++i) {
        const int r = M0 + ty * 4 + i;
        if (r < NN) {
            const float4 xv = *(const float4*)(g_xl + (size_t)r * HH + c0);
            const float4 zv = *(const float4*)(g_z + (size_t)r * HH + c0);
            const float pre[4] = {acc[i*4+0] + bb.x, acc[i*4+1] + bb.y,
                                  acc[i*4+2] + bb.z, acc[i*4+3] + bb.w};
            const float xa[4] = {xv.x, xv.y, xv.z, xv.w};
            const float za[4] = {zv.x, zv.y, zv.z, zv.w};
            float va[4];
#pragma unroll
            for (int j = 0; j < 4; ++j) {
                float g = 1.f / (1.f + __expf(-pre[j]));
                float v = fmaxf((1.f - g) * xa[j] + g * za[j], 0.f);
                va[j] = v; cs[j] += v; cq[j] += v * v;
            }
            *(float4*)(g_obuf + (size_t)r * HH + c0) = make_float4(va[0], va[1], va[2], va[3]);
        }
    }
    if (tid < 64) { rs[tid] = 0.f; rq[tid] = 0.f; }
    __syncthreads();
#pragma unroll
    for (int j = 0; j < 4; ++j) {
        atomicAdd(&rs[tx * 4 + j], cs[j]);
        atomicAdd(&rq[tx * 4 + j], cq[j]);
    }
    __syncthreads();
    if (tid < 64) {
        atomicAdd(&g_colsum[N0 + tid], rs[tid]);
        atomicAdd(&g_colsq[N0 + tid], rq[tid]);
    }
}

// ---------------- BN apply with inline stats; re-zeroes cnt/cursor for next replay ----
__global__ __launch_bounds__(256) void bn_apply(const float* __restrict__ gamma,
                                                const float* __restrict__ beta,
                                                float* __restrict__ out) {
    if (blockIdx.x < 8) {
        int i = blockIdx.x * 256 + threadIdx.x;
        if (i < NN) { g_cnt[i] = 0; g_cursor[i] = 0; }  // consumed last by agg_feat; safe here
    }
    int i = blockIdx.x * 256 + threadIdx.x;  // exactly NN*HH
    int c = i & (HH - 1);
    float mean = g_colsum[c] * (1.f / (float)NN);
    float var = g_colsq[c] * (1.f / (float)NN) - mean * mean;
    float s = rsqrtf(var + 1e-5f) * gamma[c];
    out[i] = g_obuf[i] * s + (beta[c] - mean * s);
}

// ---------------- launch ----------------
extern "C" void kernel_launch(void* const* d_in, const int* in_sizes, int n_in,
                              void* d_out, int out_size, void* d_ws, size_t ws_size,
                              hipStream_t stream) {
    (void)d_ws; (void)ws_size; (void)n_in; (void)out_size;
    const float* x      = (const float*)d_in[0];
    const int*   ei     = (const int*)d_in[1];
    const float* w1     = (const float*)d_in[2];
    const float* b1     = (const float*)d_in[3];
    const float* w2     = (const float*)d_in[4];
    const float* b2     = (const float*)d_in[5];
    const float* w3     = (const float*)d_in[6];
    const float* b3     = (const float*)d_in[7];
    const float* gcn_w  = (const float*)d_in[8];
    const float* gcn_b  = (const float*)d_in[9];
    const float* lin_w  = (const float*)d_in[10];
    const float* lin_b  = (const float*)d_in[11];
    const float* gate_w = (const float*)d_in[12];
    const float* gate_b = (const float*)d_in[13];
    const float* bn_g   = (const float*)d_in[14];
    const float* bn_b   = (const float*)d_in[15];
    float* out = (float*)d_out;
    const int E = in_sizes[1] / 2;

    conv_chain<<<NN, 256, 0, stream>>>(x, ei, E, w1, b1, w2, b2, w3, b3);
    scan_dinv<<<1, 256, 0, stream>>>();
    bucket_fill<<<(E + 255) / 256, 256, 0, stream>>>(ei, E);
    agg_feat<<<NN / 4, 256, 0, stream>>>();

    gemm_zxl<<<dim3(HH / 64, (NN + 63) / 64, 2), 256, 0, stream>>>(gcn_w, gcn_b, lin_w, lin_b);
    gemm_gate<<<dim3(HH / 64, (NN + 63) / 64), 256, 0, stream>>>(gate_w, gate_b);

    bn_apply<<<(NN * HH) / 256, 256, 0, stream>>>(bn_g, bn_b, out);
}

// Round 7
// 365.045 us; speedup vs baseline: 1.0271x; 1.0018x over previous
//
#include <hip/hip_runtime.h>
#include <hip/hip_bf16.h>
#include <cstddef>

#define NN 2000
#define CC 4
#define LL1 5000
#define LL2 1248   /* (5000-11)/4+1 */
#define LL3 207    /* (1248-11)/6+1 */
#define FSTR 208   /* feat row stride (207 + 1 zero pad) */
#define HH 512
#define EE 64000

// ---------------- device-global scratch ----------------
__device__ float g_feat[NN * FSTR];
__device__ float g_aggf[NN * FSTR];
__device__ float g_z[NN * HH];
__device__ float g_xl[NN * HH];
__device__ float g_obuf[NN * HH];
__device__ float g_dinv[NN];
__device__ float g_colsum[HH];
__device__ float g_colsq[HH];
__device__ int   g_cnt[NN];     // zeroed by bn_apply of PREVIOUS replay (init: static 0)
__device__ int   g_cursor[NN];  // ditto
__device__ int   g_off[NN];
__device__ int   g_bucket[EE];

// ---------------- per-node conv chain: wave-autonomous, 1 barrier/node ----------
// R6 bisect conclusion: the w2r 176-float register array broke correctness
// (mechanism: pressure-induced codegen fault; source semantics were clean).
// This build = R4-exact conv (w2 via global/K$) + ONLY the edge_count move
// (after the conv loop) to finish the bisect of the second sub-change.
__global__ __launch_bounds__(256) void conv_chain(
    const float* __restrict__ x, const int* __restrict__ ei, const int E,
    const float* __restrict__ w1, const float* __restrict__ b1,
    const float* __restrict__ w2, const float* __restrict__ b2,
    const float* __restrict__ w3, const float* __restrict__ b3)
{
    __shared__ __align__(16) float sy[4][LL2];        // 19968 B  (shared: conv3 crosses waves)
    __shared__ __align__(16) float smw[4][4][256];    // 16384 B  [wave][ch][local pos] private

    const int tid  = threadIdx.x;
    const int node = blockIdx.x;
    const int wid  = tid >> 6;
    const int lane = tid & 63;

    // colsum/colsq must be zero before gemm_gate accumulates (this kernel runs first)
    if (node < 2) {
        int i = node * 256 + tid;
        g_colsum[i] = 0.f; g_colsq[i] = 0.f;
    }

    const float* xb = x + (size_t)node * (CC * LL1);

    float w1r[64], b1r[16];
#pragma unroll
    for (int i = 0; i < 64; ++i) w1r[i] = w1[i];
#pragma unroll
    for (int i = 0; i < 16; ++i) b1r[i] = b1[i];

    auto loadx = [&](int bb, float4 (&dst)[4]) {
        const int p = 244 * bb + 4 * lane;
        const bool ok = (p + 3) < LL1;
#pragma unroll
        for (int ch = 0; ch < 4; ++ch)
            dst[ch] = ok ? *(const float4*)(xb + ch * LL1 + p)
                         : make_float4(0.f, 0.f, 0.f, 0.f);
    };

    float4 xc[4], xn[4];
    int b = wid;
    if (b < 21) loadx(b, xc);

    while (b < 21) {
        const int bnx = b + 4;
        if (bnx < 21) loadx(bnx, xn);        // prefetch next block (hidden under compute)

        // ---- stage1: conv1 (k=1) + channel-group maxpool + relu, 4 positions/lane ----
        {
            float xs[4][4];
#pragma unroll
            for (int ch = 0; ch < 4; ++ch)
                *(float4*)xs[ch] = xc[ch];
#pragma unroll
            for (int g = 0; g < 4; ++g) {
                float mv[4];
#pragma unroll
                for (int li = 0; li < 4; ++li) {
                    float best = -1e30f;
#pragma unroll
                    for (int j = 0; j < 4; ++j) {
                        const int o = g * 4 + j;
                        float v = b1r[o] + w1r[o*4+0]*xs[0][li] + w1r[o*4+1]*xs[1][li]
                                         + w1r[o*4+2]*xs[2][li] + w1r[o*4+3]*xs[3][li];
                        best = fmaxf(best, v);
                    }
                    mv[li] = fmaxf(best, 0.f);
                }
                *(float4*)&smw[wid][g][4 * lane] = make_float4(mv[0], mv[1], mv[2], mv[3]);
            }
        }
        // same-wave LDS write->read: in-order DS pipe; no barrier needed

        // ---- stage2: conv2 stride 4, all 4 out-channels, T = 61*b + lane ----
        {
            const int Tg = 61 * b + lane;
            if (lane < 61 && Tg < LL2) {
                float a0 = b2[0], a1 = b2[1], a2 = b2[2], a3 = b2[3];
#pragma unroll
                for (int i = 0; i < 4; ++i) {
                    const float* mp = &smw[wid][i][4 * lane];   // local pos = 4*lane..+11
                    float4 u0 = *(const float4*)mp;
                    float4 u1 = *(const float4*)(mp + 4);
                    float4 u2 = *(const float4*)(mp + 8);
                    float v[12] = {u0.x, u0.y, u0.z, u0.w,
                                   u1.x, u1.y, u1.z, u1.w,
                                   u2.x, u2.y, u2.z, u2.w};
#pragma unroll
                    for (int k = 0; k < 11; ++k) {
                        a0 += w2[  0 + i * 11 + k] * v[k];
                        a1 += w2[ 44 + i * 11 + k] * v[k];
                        a2 += w2[ 88 + i * 11 + k] * v[k];
                        a3 += w2[132 + i * 11 + k] * v[k];
                    }
                }
                sy[0][Tg] = fmaxf(a0, 0.f);
                sy[1][Tg] = fmaxf(a1, 0.f);
                sy[2][Tg] = fmaxf(a2, 0.f);
                sy[3][Tg] = fmaxf(a3, 0.f);
            }
        }

#pragma unroll
        for (int ch = 0; ch < 4; ++ch) xc[ch] = xn[ch];
        b = bnx;
    }

    // folded edge_count AFTER conv work (the one retained R5 sub-change):
    // overlaps other blocks' conv instead of delaying the first 250 blocks.
    // g_cnt zeroed last replay by bn_apply (static 0 on first call).
    if (node < 250) {
        for (int e = node * 256 + tid; e < E; e += 250 * 256)
            atomicAdd(&g_cnt[ei[E + e]], 1);
    }

    __syncthreads();   // the ONE barrier: sy complete

    // ---- stage3: conv3 stride 6, 1 out-channel ----
    if (tid < FSTR) {
        float acc = 0.f;
        if (tid < LL3) {
            acc = b3[0];
#pragma unroll
            for (int i = 0; i < 4; ++i)
#pragma unroll
                for (int k = 0; k < 11; ++k)
                    acc += w3[i * 11 + k] * sy[i][6 * tid + k];
            acc = fmaxf(acc, 0.f);
        }
        g_feat[(size_t)node * FSTR + tid] = acc;
    }
}

// ---------------- scan + dinv (1 block, shuffle scan, 1 barrier) ----------------
__global__ __launch_bounds__(256) void scan_dinv() {
    const int tid = threadIdx.x;
    const int base = tid * 8;
    int c[8];
#pragma unroll
    for (int k = 0; k < 8; ++k) c[k] = (base + k < NN) ? g_cnt[base + k] : 0;
    int pre[8]; int s = 0;
#pragma unroll
    for (int k = 0; k < 8; ++k) { pre[k] = s; s += c[k]; }
    const int lane = tid & 63;
    int ws = s;
#pragma unroll
    for (int d = 1; d < 64; d <<= 1) {
        int t = __shfl_up(ws, d, 64);
        if (lane >= d) ws += t;
    }
    __shared__ int wsum[4];
    const int wid = tid >> 6;
    if (lane == 63) wsum[wid] = ws;
    __syncthreads();
    int woff = 0;
#pragma unroll
    for (int w = 0; w < 4; ++w) if (w < wid) woff += wsum[w];
    const int toff = woff + ws - s;
#pragma unroll
    for (int k = 0; k < 8; ++k) {
        const int i = base + k;
        if (i < NN) {
            g_off[i] = toff + pre[k];
            g_dinv[i] = rsqrtf(1.0f + (float)c[k]);
        }
    }
}

__global__ void bucket_fill(const int* __restrict__ ei, int E) {
    int e = blockIdx.x * 256 + threadIdx.x;
    if (e < E) {
        int d = ei[E + e];
        int p = atomicAdd(&g_cursor[d], 1);
        g_bucket[g_off[d] + p] = ei[e];
    }
}

// ---------------- aggregate feat over graph (float4 gathers, 4 nodes/block) -------
// R4-exact
__global__ __launch_bounds__(256) void agg_feat() {
    const int sub = threadIdx.x >> 6;
    const int lane = threadIdx.x & 63;
    const int d = blockIdx.x * 4 + sub;          // grid 500 -> d < 2000
    if (lane >= 52) return;
    const float di = g_dinv[d];
    const int nb = g_cnt[d];
    const int base = g_off[d];
    const size_t co = (size_t)lane * 4;
    float4 a = *(const float4*)(g_feat + (size_t)d * FSTR + co);
    float ax = a.x * di, ay = a.y * di, az = a.z * di, aw = a.w * di;
    int j = 0;
    for (; j + 1 < nb; j += 2) {
        int s0 = g_bucket[base + j];
        int s1 = g_bucket[base + j + 1];
        float w0 = g_dinv[s0], w1 = g_dinv[s1];
        float4 f0 = *(const float4*)(g_feat + (size_t)s0 * FSTR + co);
        float4 f1 = *(const float4*)(g_feat + (size_t)s1 * FSTR + co);
        ax += f0.x * w0 + f1.x * w1;
        ay += f0.y * w0 + f1.y * w1;
        az += f0.z * w0 + f1.z * w1;
        aw += f0.w * w0 + f1.w * w1;
    }
    if (j < nb) {
        int s = g_bucket[base + j];
        float w = g_dinv[s];
        float4 f = *(const float4*)(g_feat + (size_t)s * FSTR + co);
        ax += f.x * w; ay += f.y * w; az += f.z * w; aw += f.w * w;
    }
    *(float4*)(g_aggf + (size_t)d * FSTR + co) = make_float4(ax * di, ay * di, az * di, aw * di);
}

// ---------------- GEMM 64x64 tile, 256 thr, 4x4 micro-tile, dbuf ----------------
__global__ __launch_bounds__(256) void gemm_zxl(
    const float* __restrict__ gcn_w, const float* __restrict__ gcn_b,
    const float* __restrict__ lin_w, const float* __restrict__ lin_b)
{
    __shared__ __align__(16) float As[2][16][68];
    __shared__ __align__(16) float Bs[2][16][68];
    const int tid = threadIdx.x;
    const int which = blockIdx.z;
    const float* __restrict__ A = which ? g_feat : g_aggf;
    const float* __restrict__ B = which ? lin_w : gcn_w;
    const float* __restrict__ bias = which ? lin_b : gcn_b;
    float* __restrict__ C = which ? g_xl : g_z;
    const int N0 = blockIdx.x * 64, M0 = blockIdx.y * 64;
    const int ar = tid >> 2, ak = (tid & 3) * 4;   // A loader
    const int bk = tid >> 4, bn = (tid & 15) * 4;  // B loader
    const int ty = tid >> 4, tx = tid & 15;        // compute 4x4
    const int rowA = M0 + ar;

    float acc[16];
#pragma unroll
    for (int i = 0; i < 16; ++i) acc[i] = 0.f;
    const float4 z4 = make_float4(0.f, 0.f, 0.f, 0.f);
    float4 rA, rB;

    rA = (rowA < NN) ? *(const float4*)(A + (size_t)rowA * FSTR + ak) : z4;
    rB = (bk < LL3) ? *(const float4*)(B + (size_t)bk * HH + N0 + bn) : z4;
    As[0][ak+0][ar] = rA.x; As[0][ak+1][ar] = rA.y;
    As[0][ak+2][ar] = rA.z; As[0][ak+3][ar] = rA.w;
    *(float4*)&Bs[0][bk][bn] = rB;
    __syncthreads();

#pragma unroll 1
    for (int kt = 0; kt < 13; ++kt) {              // 13*16 = 208 = FSTR (pad col = 0)
        const int cur = kt & 1;
        if (kt + 1 < 13) {
            const int k0 = (kt + 1) * 16;
            rA = (rowA < NN) ? *(const float4*)(A + (size_t)rowA * FSTR + k0 + ak) : z4;
            const int kb = k0 + bk;
            rB = (kb < LL3) ? *(const float4*)(B + (size_t)kb * HH + N0 + bn) : z4;
        }
#pragma unroll
        for (int k = 0; k < 16; ++k) {
            const float4 a4 = *(const float4*)&As[cur][k][ty * 4];
            const float4 b4 = *(const float4*)&Bs[cur][k][tx * 4];
            const float av[4] = {a4.x, a4.y, a4.z, a4.w};
            const float bv[4] = {b4.x, b4.y, b4.z, b4.w};
#pragma unroll
            for (int i = 0; i < 4; ++i)
#pragma unroll
                for (int j = 0; j < 4; ++j)
                    acc[i * 4 + j] += av[i] * bv[j];
        }
        if (kt + 1 < 13) {
            const int nxt = cur ^ 1;
            As[nxt][ak+0][ar] = rA.x; As[nxt][ak+1][ar] = rA.y;
            As[nxt][ak+2][ar] = rA.z; As[nxt][ak+3][ar] = rA.w;
            *(float4*)&Bs[nxt][bk][bn] = rB;
        }
        __syncthreads();
    }

    const int c0 = N0 + tx * 4;
    const float4 bb = *(const float4*)(bias + c0);
#pragma unroll
    for (int i = 0; i < 4; ++i) {
        const int r = M0 + ty * 4 + i;
        if (r < NN) {
            float4 v = make_float4(acc[i*4+0] + bb.x, acc[i*4+1] + bb.y,
                                   acc[i*4+2] + bb.z, acc[i*4+3] + bb.w);
            if (which == 0) { v.x = tanhf(v.x); v.y = tanhf(v.y); v.z = tanhf(v.z); v.w = tanhf(v.w); }
            *(float4*)(C + (size_t)r * HH + c0) = v;
        }
    }
}

// gate GEMM: gpre = z @ gate_w + gate_b, fused sigmoid-gate/residual/relu/colsums
// R4-exact 64x64
__global__ __launch_bounds__(256) void gemm_gate(
    const float* __restrict__ gate_w, const float* __restrict__ gate_b)
{
    __shared__ __align__(16) float As[2][16][68];
    __shared__ __align__(16) float Bs[2][16][68];
    __shared__ float rs[64], rq[64];
    const int tid = threadIdx.x;
    const float* __restrict__ A = g_z;
    const int N0 = blockIdx.x * 64, M0 = blockIdx.y * 64;
    const int ar = tid >> 2, ak = (tid & 3) * 4;
    const int bk = tid >> 4, bn = (tid & 15) * 4;
    const int ty = tid >> 4, tx = tid & 15;
    const int rowA = M0 + ar;

    float acc[16];
#pragma unroll
    for (int i = 0; i < 16; ++i) acc[i] = 0.f;
    const float4 z4 = make_float4(0.f, 0.f, 0.f, 0.f);
    float4 rA, rB;

    rA = (rowA < NN) ? *(const float4*)(A + (size_t)rowA * HH + ak) : z4;
    rB = *(const float4*)(gate_w + (size_t)bk * HH + N0 + bn);
    As[0][ak+0][ar] = rA.x; As[0][ak+1][ar] = rA.y;
    As[0][ak+2][ar] = rA.z; As[0][ak+3][ar] = rA.w;
    *(float4*)&Bs[0][bk][bn] = rB;
    __syncthreads();

#pragma unroll 1
    for (int kt = 0; kt < 32; ++kt) {              // 32*16 = 512 = HH
        const int cur = kt & 1;
        if (kt + 1 < 32) {
            const int k0 = (kt + 1) * 16;
            rA = (rowA < NN) ? *(const float4*)(A + (size_t)rowA * HH + k0 + ak) : z4;
            rB = *(const float4*)(gate_w + (size_t)(k0 + bk) * HH + N0 + bn);
        }
#pragma unroll
        for (int k = 0; k < 16; ++k) {
            const float4 a4 = *(const float4*)&As[cur][k][ty * 4];
            const float4 b4 = *(const float4*)&Bs[cur][k][tx * 4];
            const float av[4] = {a4.x, a4.y, a4.z, a4.w};
            const float bv[4] = {b4.x, b4.y, b4.z, b4.w};
#pragma unroll
            for (int i = 0; i < 4; ++i)
#pragma unroll
                for (int j = 0; j < 4; ++j)
                    acc[i * 4 + j] += av[i] * bv[j];
        }
        if (kt + 1 < 32) {
            const int nxt = cur ^ 1;
            As[nxt][ak+0][ar] = rA.x; As[nxt][ak+1][ar] = rA.y;
            As[nxt][ak+2][ar] = rA.z; As[nxt][ak+3][ar] = rA.w;
            *(float4*)&Bs[nxt][bk][bn] = rB;
        }
        __syncthreads();
    }

    const int c0 = N0 + tx * 4;
    const float4 bb = *(const float4*)(gate_b + c0);
    float cs[4] = {0.f, 0.f, 0.f, 0.f}, cq[4] = {0.f, 0.f, 0.f, 0.f};
#pragma unroll
    for (int i = 0; i < 4; ++i) {
        const int r = M0 + ty * 4 + i;
        if (r < NN) {
            const float4 xv = *(const float4*)(g_xl + (size_t)r * HH + c0);
            const float4 zv = *(const float4*)(g_z + (size_t)r * HH + c0);
            const float pre[4] = {acc[i*4+0] + bb.x, acc[i*4+1] + bb.y,
                                  acc[i*4+2] + bb.z, acc[i*4+3] + bb.w};
            const float xa[4] = {xv.x, xv.y, xv.z, xv.w};
            const float za[4] = {zv.x, zv.y, zv.z, zv.w};
            float va[4];
#pragma unroll
            for (int j = 0; j < 4; ++j) {
                float g = 1.f / (1.f + __expf(-pre[j]));
                float v = fmaxf((1.f - g) * xa[j] + g * za[j], 0.f);
                va[j] = v; cs[j] += v; cq[j] += v * v;
            }
            *(float4*)(g_obuf + (size_t)r * HH + c0) = make_float4(va[0], va[1], va[2], va[3]);
        }
    }
    if (tid < 64) { rs[tid] = 0.f; rq[tid] = 0.f; }
    __syncthreads();
#pragma unroll
    for (int j = 0; j < 4; ++j) {
        atomicAdd(&rs[tx * 4 + j], cs[j]);
        atomicAdd(&rq[tx * 4 + j], cq[j]);
    }
    __syncthreads();
    if (tid < 64) {
        atomicAdd(&g_colsum[N0 + tid], rs[tid]);
        atomicAdd(&g_colsq[N0 + tid], rq[tid]);
    }
}

// ---------------- BN apply with inline stats; re-zeroes cnt/cursor for next replay ----
__global__ __launch_bounds__(256) void bn_apply(const float* __restrict__ gamma,
                                                const float* __restrict__ beta,
                                                float* __restrict__ out) {
    if (blockIdx.x < 8) {
        int i = blockIdx.x * 256 + threadIdx.x;
        if (i < NN) { g_cnt[i] = 0; g_cursor[i] = 0; }  // consumed last by agg_feat; safe here
    }
    int i = blockIdx.x * 256 + threadIdx.x;  // exactly NN*HH
    int c = i & (HH - 1);
    float mean = g_colsum[c] * (1.f / (float)NN);
    float var = g_colsq[c] * (1.f / (float)NN) - mean * mean;
    float s = rsqrtf(var + 1e-5f) * gamma[c];
    out[i] = g_obuf[i] * s + (beta[c] - mean * s);
}

// ---------------- launch ----------------
extern "C" void kernel_launch(void* const* d_in, const int* in_sizes, int n_in,
                              void* d_out, int out_size, void* d_ws, size_t ws_size,
                              hipStream_t stream) {
    (void)d_ws; (void)ws_size; (void)n_in; (void)out_size;
    const float* x      = (const float*)d_in[0];
    const int*   ei     = (const int*)d_in[1];
    const float* w1     = (const float*)d_in[2];
    const float* b1     = (const float*)d_in[3];
    const float* w2     = (const float*)d_in[4];
    const float* b2     = (const float*)d_in[5];
    const float* w3     = (const float*)d_in[6];
    const float* b3     = (const float*)d_in[7];
    const float* gcn_w  = (const float*)d_in[8];
    const float* gcn_b  = (const float*)d_in[9];
    const float* lin_w  = (const float*)d_in[10];
    const float* lin_b  = (const float*)d_in[11];
    const float* gate_w = (const float*)d_in[12];
    const float* gate_b = (const float*)d_in[13];
    const float* bn_g   = (const float*)d_in[14];
    const float* bn_b   = (const float*)d_in[15];
    float* out = (float*)d_out;
    const int E = in_sizes[1] / 2;

    conv_chain<<<NN, 256, 0, stream>>>(x, ei, E, w1, b1, w2, b2, w3, b3);
    scan_dinv<<<1, 256, 0, stream>>>();
    bucket_fill<<<(E + 255) / 256, 256, 0, stream>>>(ei, E);
    agg_feat<<<NN / 4, 256, 0, stream>>>();

    gemm_zxl<<<dim3(HH / 64, (NN + 63) / 64, 2), 256, 0, stream>>>(gcn_w, gcn_b, lin_w, lin_b);
    gemm_gate<<<dim3(HH / 64, (NN + 63) / 64), 256, 0, stream>>>(gate_w, gate_b);

    bn_apply<<<(NN * HH) / 256, 256, 0, stream>>>(bn_g, bn_b, out);
}